// Round 12
// baseline (558.422 us; speedup 1.0000x reference)
//
#include <hip/hip_runtime.h>
#include <hip/hip_bf16.h>
#include <cmath>
#include <cstdint>

// AttentionPoolingAggregator — MI355X round 16
//  * gemm accepted at ~119us (7 structural levers all neutral; mixed-stream
//    plateau ~3.5TB/s app traffic). This round deletes/hides SERIAL work:
//    (1) W hi/lo split now done in-register inside gemm (same bytes, deletes
//        the wsplit half of prep + its workspace arrays);
//    (2) fill (sorted-edge scatter, ~25us latency-bound) fused into the gemm
//        prologue — each block scatters a 1250-edge slice before its W loads;
//        hides under the 119us persistent gemm. scan still runs before gemm;
//        edge is stream-ordered after.
//  * edge_flash / scan unchanged; prep shrinks to histogram-only.

#define H 256

typedef __attribute__((ext_vector_type(8))) short bfrag;  // 8 bf16 (4 VGPRs)
typedef __attribute__((ext_vector_type(4))) float ffrag;  // 4 fp32 acc

__device__ __forceinline__ ushort f2bf(float f) {  // fp32 -> bf16 RNE
  uint u = __float_as_uint(f);
  uint r = u + 0x7FFFu + ((u >> 16) & 1u);
  return (ushort)(r >> 16);
}
__device__ __forceinline__ float bf2f(ushort h) {
  return __uint_as_float((uint)h << 16);
}

// ---------------- histogram only (wsplit moved into gemm) ----------------
__global__ void hist_kernel(const int* __restrict__ dst, int* __restrict__ counts, int E) {
  int e = blockIdx.x * blockDim.x + threadIdx.x;
  if (e < E) atomicAdd(&counts[dst[e]], 1);
}

// single-block scan over C counts -> exclusive offsets[0..C], cursor copy
__global__ void scan_kernel(const int* __restrict__ counts, int* __restrict__ offsets,
                            int* __restrict__ cursor, int C) {
  __shared__ int wsum[16];
  int tid = threadIdx.x;
  int lane = tid & 63, wid = tid >> 6;
  int base = 0;
  for (int start = 0; start < C; start += 1024) {
    int idx = start + tid;
    int val = (idx < C) ? counts[idx] : 0;
    int x = val;
#pragma unroll
    for (int off = 1; off < 64; off <<= 1) {
      int y = __shfl_up(x, off);
      if (lane >= off) x += y;
    }
    if (lane == 63) wsum[wid] = x;
    __syncthreads();
    int add = base;
    for (int w = 0; w < wid; ++w) add += wsum[w];
    if (idx < C) {
      int excl = add + x - val;
      offsets[idx] = excl;
      cursor[idx]  = excl;
    }
    int tot = 0;
#pragma unroll
    for (int w = 0; w < 16; ++w) tot += wsum[w];
    __syncthreads();
    base += tot;
  }
  if (tid == 0) offsets[C] = base;
}

// ---------------- persistent-W MFMA GEMM + fused fill + in-reg wsplit ----------------
__global__ __launch_bounds__(1024, 1) void gemm_persist(
    const float* __restrict__ Xc, const float* __restrict__ Wc,
    ushort* __restrict__ cproj, int MC, int GC,
    const float* __restrict__ Xn, const float* __restrict__ Wn,
    ushort* __restrict__ nproj, ushort* __restrict__ nxbf, int MN,
    const int* __restrict__ esrc, const int* __restrict__ edst,
    int* __restrict__ cursor, int* __restrict__ srcs_sorted, int E) {
  constexpr int PITCH = 264;              // ushorts per LDS row (528B = 33*16B)
  __shared__ ushort Xs[2][64 * PITCH];    // 2 x 33.8 KB double buffer (67.6 KB)
  const int tid = threadIdx.x;
  const int wv = tid >> 6, lane = tid & 63;   // wv 0..15: owns cols wv*16..+15
  const int q = lane >> 4, nidx = lane & 15;
  const int GN = gridDim.x - GC;

  // ---- fused fill: scatter this block's edge slice (hides under gemm) ----
  {
    const int B = gridDim.x;
    const int e0 = (int)(((long long)blockIdx.x * E) / B);
    const int e1 = (int)(((long long)(blockIdx.x + 1) * E) / B);
    for (int e = e0 + tid; e < e1; e += 1024) {
      const int d = edst[e];
      const int pos = atomicAdd(&cursor[d], 1);
      srcs_sorted[pos] = esrc[e];
    }
  }

  const float* X; const float* W; ushort *proj, *xb; int M, nb, lb;
  if ((int)blockIdx.x < GC) {
    X = Xc; W = Wc; proj = cproj; xb = nullptr; M = MC;
    nb = GC; lb = blockIdx.x;
  } else {
    X = Xn; W = Wn; proj = nproj; xb = nxbf; M = MN;
    nb = GN; lb = blockIdx.x - GC;
  }
  const int nt = (M + 63) >> 6;                       // tiles for this side
  const int qt = nt / nb, rt = nt % nb;
  const int first = lb * qt + (lb < rt ? lb : rt);    // contiguous chunk
  const int cnt = qt + (lb < rt ? 1 : 0);
  if (cnt <= 0) return;

  // ---- persistent W fragments, split hi/lo IN REGISTER from fp32 ----
  bfrag bhi[8], blo[8];  // 16 bfrags = 64 VGPRs
  {
    const float* Wp = W + (size_t)(wv * 16 + nidx) * H + q * 8;
#pragma unroll
    for (int ks = 0; ks < 8; ++ks) {
      const float4 w0 = *(const float4*)(Wp + ks * 32);
      const float4 w1 = *(const float4*)(Wp + ks * 32 + 4);
      const float wf[8] = {w0.x, w0.y, w0.z, w0.w, w1.x, w1.y, w1.z, w1.w};
#pragma unroll
      for (int j = 0; j < 8; ++j) {
        const ushort h = f2bf(wf[j]);
        bhi[ks][j] = (short)h;
        blo[ks][j] = (short)f2bf(wf[j] - bf2f(h));
      }
    }
  }

  float4 xr[4];  // staging: 64x256 fp32 tile / 1024 thr = 4 float4 each
  auto load4 = [&](int tile) {
#pragma unroll
    for (int j = 0; j < 4; ++j) {
      const int flat = j * 4096 + tid * 4;            // fully coalesced 16B/lane
      int gr = tile * 64 + (flat >> 8);
      if (gr >= M) gr = M - 1;                        // company tail: dup reads
      xr[j] = *(const float4*)(X + (size_t)gr * H + (flat & 255));
    }
  };
  auto writebuf = [&](int p, int tile) {
#pragma unroll
    for (int j = 0; j < 4; ++j) {
      const int flat = j * 4096 + tid * 4;
      const int r = flat >> 8, k = flat & 255;
      ushort4 b4;
      b4.x = f2bf(xr[j].x); b4.y = f2bf(xr[j].y);
      b4.z = f2bf(xr[j].z); b4.w = f2bf(xr[j].w);
      *(ushort4*)&Xs[p][r * PITCH + k] = b4;
      if (xb) {
        const int gr = tile * 64 + r;                 // news: full tiles, no clamp
        *(ushort4*)(xb + (size_t)gr * H + k) = b4;
      }
    }
  };

  // prologue: stage first tile into buffer 0
  load4(first);
  writebuf(0, first);
  int p = 0;
  for (int t = 0; t < cnt; ++t) {
    __syncthreads();                                  // buf[p] ready; buf[p^1] free
    const int tile = first + t;
    const bool more = (t + 1 < cnt);
    if (more) load4(tile + 1);

    ffrag acc[4];
#pragma unroll
    for (int i = 0; i < 4; ++i) acc[i] = (ffrag)(0.f);
#pragma unroll
    for (int ks = 0; ks < 8; ++ks) {
      bfrag a[4];
#pragma unroll
      for (int i = 0; i < 4; ++i)
        a[i] = *(const bfrag*)&Xs[p][(16 * i + nidx) * PITCH + ks * 32 + q * 8];
#pragma unroll
      for (int i = 0; i < 4; ++i) {
        acc[i] = __builtin_amdgcn_mfma_f32_16x16x32_bf16(a[i], bhi[ks], acc[i], 0, 0, 0);
        acc[i] = __builtin_amdgcn_mfma_f32_16x16x32_bf16(a[i], blo[ks], acc[i], 0, 0, 0);
      }
    }

    const int row0 = tile * 64;
#pragma unroll
    for (int i = 0; i < 4; ++i)
#pragma unroll
      for (int r = 0; r < 4; ++r) {
        const int grow = row0 + 16 * i + q * 4 + r;
        if (grow < M)
          proj[(size_t)grow * H + wv * 16 + nidx] = f2bf(acc[i][r]);
      }

    if (more) writebuf(p ^ 1, tile + 1);              // write-late into free buffer
    p ^= 1;
  }
}

// ---------------- split-wave flash edge kernel ----------------
// 4 instrs (2 trans), no IEEE div:  tanh(x) = 1 - 2*rcp(exp2(2x*log2e)+1)
__device__ __forceinline__ float fast_tanh(float x) {
  float e = __builtin_amdgcn_exp2f(x * 2.8853900817779268f);  // e^{2x}
  float t = __builtin_amdgcn_rcpf(e + 1.f);
  return __builtin_fmaf(-2.f, t, 1.f);
}

__global__ __launch_bounds__(256) void edge_flash_kernel(
    const ushort* __restrict__ news_projbf, const ushort* __restrict__ company_projbf,
    const float* __restrict__ v, const int* __restrict__ offsets,
    const int* __restrict__ srcs, const ushort* __restrict__ news_xbf,
    float* __restrict__ out) {
  const int c = blockIdx.x;
  const int tid = threadIdx.x;
  const int sl = tid & 31;   // sub-lane within half-wave (owns dims sl*8..sl*8+7)
  const int hw = tid >> 5;   // half-wave id 0..7 (owns edges beg+hw, +8, +16, ...)
  __shared__ float cp[H];
  __shared__ float mW[8], lW[8];
  __shared__ float OW[8][H];  // 8 KB
  cp[tid] = bf2f(company_projbf[(size_t)c * H + tid]);
  __syncthreads();
  const float4 va = *(const float4*)(v + sl * 8);
  const float4 vb = *(const float4*)(v + sl * 8 + 4);
  const float4 ca = *(const float4*)&cp[sl * 8];
  const float4 cb = *(const float4*)&cp[sl * 8 + 4];
  const float vv[8] = {va.x, va.y, va.z, va.w, vb.x, vb.y, vb.z, vb.w};
  const float cq[8] = {ca.x, ca.y, ca.z, ca.w, cb.x, cb.y, cb.z, cb.w};
  const int beg = offsets[c], end = offsets[c + 1];

  float m = -INFINITY, l = 0.f;
  float O[8] = {0.f, 0.f, 0.f, 0.f, 0.f, 0.f, 0.f, 0.f};

  int i = beg + hw;
  if (i < end) {
    int s = srcs[i];
    bfrag pr = *(const bfrag*)(news_projbf + (size_t)s * H + sl * 8);
    bfrag xr = *(const bfrag*)(news_xbf + (size_t)s * H + sl * 8);
    for (;;) {
      const int inext = i + 8;
      const bool more = (inext < end);  // half-wave uniform
      bfrag prn, xrn;
      if (more) {  // prefetch next edge while computing current
        int sn = srcs[inext];
        prn = *(const bfrag*)(news_projbf + (size_t)sn * H + sl * 8);
        xrn = *(const bfrag*)(news_xbf + (size_t)sn * H + sl * 8);
      }
      float r = 0.f;
#pragma unroll
      for (int j = 0; j < 8; ++j)
        r += fast_tanh(bf2f((ushort)pr[j]) + cq[j]) * vv[j];
#pragma unroll
      for (int off = 16; off > 0; off >>= 1) r += __shfl_xor(r, off);
      const float mnew = fmaxf(m, r);
      const float alpha = __expf(m - mnew);  // first iter: exp(-inf)=0
      const float pa = __expf(r - mnew);
      l = l * alpha + pa;
#pragma unroll
      for (int j = 0; j < 8; ++j)
        O[j] = O[j] * alpha + pa * bf2f((ushort)xr[j]);
      m = mnew;
      i = inext;
      if (!more) break;
      pr = prn; xr = xrn;
    }
  }

  // ---- merge 8 half-waves ----
  if (sl == 0) { mW[hw] = m; lW[hw] = l; }
  *(float4*)&OW[hw][sl * 8]     = make_float4(O[0], O[1], O[2], O[3]);
  *(float4*)&OW[hw][sl * 8 + 4] = make_float4(O[4], O[5], O[6], O[7]);
  __syncthreads();
  float mstar = -INFINITY;
#pragma unroll
  for (int w = 0; w < 8; ++w) mstar = fmaxf(mstar, mW[w]);
  float denom = 0.f, val = 0.f;
#pragma unroll
  for (int w = 0; w < 8; ++w) {
    const float sc = (lW[w] > 0.f) ? __expf(mW[w] - mstar) : 0.f;
    denom += lW[w] * sc;
    val += OW[w][tid] * sc;
  }
  out[(size_t)c * H + tid] = val / fmaxf(denom, 1e-9f);
}

// ---------------- launch ----------------
extern "C" void kernel_launch(void* const* d_in, const int* in_sizes, int n_in,
                              void* d_out, int out_size, void* d_ws, size_t ws_size,
                              hipStream_t stream) {
  const float* news_x    = (const float*)d_in[0];
  const float* company_x = (const float*)d_in[1];
  const float* W_news    = (const float*)d_in[2];
  const float* W_company = (const float*)d_in[3];
  const float* v         = (const float*)d_in[4];
  const int*   src       = (const int*)d_in[5];
  const int*   dst       = (const int*)d_in[6];
  const int N = in_sizes[0] / H;
  const int C = in_sizes[1] / H;
  const int E = in_sizes[5];
  float* out = (float*)d_out;

  char* p = (char*)d_ws;
  ushort* news_projbf    = (ushort*)p; p += (size_t)N * H * sizeof(ushort);
  ushort* news_xbf       = (ushort*)p; p += (size_t)N * H * sizeof(ushort);
  ushort* company_projbf = (ushort*)p; p += (size_t)C * H * sizeof(ushort);
  int*    srcs_sorted    = (int*)p;    p += (size_t)E * sizeof(int);
  int*    counts         = (int*)p;    p += (size_t)C * sizeof(int);
  int*    offsets        = (int*)p;    p += (size_t)(C + 1) * sizeof(int);
  int*    cursor         = (int*)p;    p += (size_t)C * sizeof(int);

  hipMemsetAsync(counts, 0, (size_t)C * sizeof(int), stream);
  hist_kernel<<<(E + 255) / 256, 256, 0, stream>>>(dst, counts, E);
  scan_kernel<<<1, 1024, 0, stream>>>(counts, offsets, cursor, C);

  // 512 blocks x 1024 thr (2/CU). Fill is fused into the gemm prologue;
  // scan completed above, edge is stream-ordered after.
  const int GC = 24, GN = 488;
  gemm_persist<<<GC + GN, 1024, 0, stream>>>(
      company_x, W_company, company_projbf, C, GC,
      news_x, W_news, news_projbf, news_xbf, N,
      src, dst, cursor, srcs_sorted, E);

  edge_flash_kernel<<<C, 256, 0, stream>>>(news_projbf, company_projbf, v, offsets,
                                           srcs_sorted, news_xbf, out);
}

// Round 13
// 531.672 us; speedup vs baseline: 1.0503x; 1.0503x over previous
//
#include <hip/hip_runtime.h>
#include <hip/hip_bf16.h>
#include <cmath>
#include <cstdint>

// AttentionPoolingAggregator — MI355X round 17
//  * r16 fusion REVERTED: scattered 4B stores + cursor atomics inside gemm
//    caused partial-line RMW amplification (WRITE +149MB, FETCH +59MB) and
//    stole the gemm's bandwidth for its whole lifetime (119->190us). Scatter
//    work stays in its own compact fill kernel.
//  * Structure = round-15 best (total 535): prep(wsplit+hist) -> scan ->
//    fill -> gemm_persist (16 waves x 16 cols, VGPR 64, 512 blocks) -> edge.
//  * ONE change: edge gather pipeline deepened 1 -> 2 edges ahead (6 loads
//    in flight per wave). If the ~880cyc/edge-iter has exposed HBM latency,
//    this cuts it; VGPR 32 -> ~48, occupancy unaffected.

#define H 256

typedef __attribute__((ext_vector_type(8))) short bfrag;  // 8 bf16 (4 VGPRs)
typedef __attribute__((ext_vector_type(4))) float ffrag;  // 4 fp32 acc

__device__ __forceinline__ ushort f2bf(float f) {  // fp32 -> bf16 RNE
  uint u = __float_as_uint(f);
  uint r = u + 0x7FFFu + ((u >> 16) & 1u);
  return (ushort)(r >> 16);
}
__device__ __forceinline__ float bf2f(ushort h) {
  return __uint_as_float((uint)h << 16);
}

// ---------------- prep: wsplit(W_news) | wsplit(W_company) | count histogram ----------------
__global__ void prep_kernel(const float* __restrict__ Wn, const float* __restrict__ Wc,
                            ushort* __restrict__ WnHi, ushort* __restrict__ WnLo,
                            ushort* __restrict__ WcHi, ushort* __restrict__ WcLo,
                            const int* __restrict__ dst, int* __restrict__ counts, int E) {
  const int b = blockIdx.x, tid = threadIdx.x;
  if (b < 256) {
    int i = b * 256 + tid;
    float w = Wn[i];
    ushort h = f2bf(w);
    WnHi[i] = h;
    WnLo[i] = f2bf(w - bf2f(h));
  } else if (b < 512) {
    int i = (b - 256) * 256 + tid;
    float w = Wc[i];
    ushort h = f2bf(w);
    WcHi[i] = h;
    WcLo[i] = f2bf(w - bf2f(h));
  } else {
    int e = (b - 512) * 256 + tid;
    if (e < E) atomicAdd(&counts[dst[e]], 1);
  }
}

// single-block scan over C counts -> exclusive offsets[0..C], cursor copy
__global__ void scan_kernel(const int* __restrict__ counts, int* __restrict__ offsets,
                            int* __restrict__ cursor, int C) {
  __shared__ int wsum[16];
  int tid = threadIdx.x;
  int lane = tid & 63, wid = tid >> 6;
  int base = 0;
  for (int start = 0; start < C; start += 1024) {
    int idx = start + tid;
    int val = (idx < C) ? counts[idx] : 0;
    int x = val;
#pragma unroll
    for (int off = 1; off < 64; off <<= 1) {
      int y = __shfl_up(x, off);
      if (lane >= off) x += y;
    }
    if (lane == 63) wsum[wid] = x;
    __syncthreads();
    int add = base;
    for (int w = 0; w < wid; ++w) add += wsum[w];
    if (idx < C) {
      int excl = add + x - val;
      offsets[idx] = excl;
      cursor[idx]  = excl;
    }
    int tot = 0;
#pragma unroll
    for (int w = 0; w < 16; ++w) tot += wsum[w];
    __syncthreads();
    base += tot;
  }
  if (tid == 0) offsets[C] = base;
}

__global__ void fill_kernel(const int* __restrict__ src, const int* __restrict__ dst,
                            int* __restrict__ cursor, int* __restrict__ srcs_sorted, int E) {
  int e = blockIdx.x * blockDim.x + threadIdx.x;
  if (e < E) {
    int d = dst[e];
    int pos = atomicAdd(&cursor[d], 1);
    srcs_sorted[pos] = src[e];
  }
}

// ---------------- persistent-W MFMA GEMM: 16 waves x 16 cols ----------------
__global__ __launch_bounds__(1024, 1) void gemm_persist(
    const float* __restrict__ Xc, const ushort* __restrict__ WcHi,
    const ushort* __restrict__ WcLo, ushort* __restrict__ cproj, int MC, int GC,
    const float* __restrict__ Xn, const ushort* __restrict__ WnHi,
    const ushort* __restrict__ WnLo, ushort* __restrict__ nproj,
    ushort* __restrict__ nxbf, int MN) {
  constexpr int PITCH = 264;              // ushorts per LDS row (528B = 33*16B)
  __shared__ ushort Xs[2][64 * PITCH];    // 2 x 33.8 KB double buffer (67.6 KB)
  const int tid = threadIdx.x;
  const int wv = tid >> 6, lane = tid & 63;   // wv 0..15: owns cols wv*16..+15
  const int q = lane >> 4, nidx = lane & 15;
  const int GN = gridDim.x - GC;

  const float* X; const ushort *Whi, *Wlo; ushort *proj, *xb; int M, nb, lb;
  if ((int)blockIdx.x < GC) {
    X = Xc; Whi = WcHi; Wlo = WcLo; proj = cproj; xb = nullptr; M = MC;
    nb = GC; lb = blockIdx.x;
  } else {
    X = Xn; Whi = WnHi; Wlo = WnLo; proj = nproj; xb = nxbf; M = MN;
    nb = GN; lb = blockIdx.x - GC;
  }
  const int nt = (M + 63) >> 6;                       // tiles for this side
  const int qt = nt / nb, rt = nt % nb;
  const int first = lb * qt + (lb < rt ? lb : rt);    // contiguous chunk
  const int cnt = qt + (lb < rt ? 1 : 0);
  if (cnt <= 0) return;

  // ---- persistent W fragments: this wave's 16 output cols, hi+lo, 8 k-slices ----
  bfrag bhi[8], blo[8];  // 16 bfrags = 64 VGPRs
#pragma unroll
  for (int ks = 0; ks < 8; ++ks) {
    const size_t off = (size_t)(wv * 16 + nidx) * H + ks * 32 + q * 8;
    bhi[ks] = *(const bfrag*)(Whi + off);
    blo[ks] = *(const bfrag*)(Wlo + off);
  }

  float4 xr[4];  // staging: 64x256 fp32 tile / 1024 thr = 4 float4 each
  auto load4 = [&](int tile) {
#pragma unroll
    for (int j = 0; j < 4; ++j) {
      const int flat = j * 4096 + tid * 4;            // fully coalesced 16B/lane
      int gr = tile * 64 + (flat >> 8);
      if (gr >= M) gr = M - 1;                        // company tail: dup reads
      xr[j] = *(const float4*)(X + (size_t)gr * H + (flat & 255));
    }
  };
  auto writebuf = [&](int p, int tile) {
#pragma unroll
    for (int j = 0; j < 4; ++j) {
      const int flat = j * 4096 + tid * 4;
      const int r = flat >> 8, k = flat & 255;
      ushort4 b4;
      b4.x = f2bf(xr[j].x); b4.y = f2bf(xr[j].y);
      b4.z = f2bf(xr[j].z); b4.w = f2bf(xr[j].w);
      *(ushort4*)&Xs[p][r * PITCH + k] = b4;
      if (xb) {
        const int gr = tile * 64 + r;                 // news: full tiles, no clamp
        *(ushort4*)(xb + (size_t)gr * H + k) = b4;
      }
    }
  };

  // prologue: stage first tile into buffer 0
  load4(first);
  writebuf(0, first);
  int p = 0;
  for (int t = 0; t < cnt; ++t) {
    __syncthreads();                                  // buf[p] ready; buf[p^1] free
    const int tile = first + t;
    const bool more = (t + 1 < cnt);
    if (more) load4(tile + 1);

    ffrag acc[4];
#pragma unroll
    for (int i = 0; i < 4; ++i) acc[i] = (ffrag)(0.f);
#pragma unroll
    for (int ks = 0; ks < 8; ++ks) {
      bfrag a[4];
#pragma unroll
      for (int i = 0; i < 4; ++i)
        a[i] = *(const bfrag*)&Xs[p][(16 * i + nidx) * PITCH + ks * 32 + q * 8];
#pragma unroll
      for (int i = 0; i < 4; ++i) {
        acc[i] = __builtin_amdgcn_mfma_f32_16x16x32_bf16(a[i], bhi[ks], acc[i], 0, 0, 0);
        acc[i] = __builtin_amdgcn_mfma_f32_16x16x32_bf16(a[i], blo[ks], acc[i], 0, 0, 0);
      }
    }

    const int row0 = tile * 64;
#pragma unroll
    for (int i = 0; i < 4; ++i)
#pragma unroll
      for (int r = 0; r < 4; ++r) {
        const int grow = row0 + 16 * i + q * 4 + r;
        if (grow < M)
          proj[(size_t)grow * H + wv * 16 + nidx] = f2bf(acc[i][r]);
      }

    if (more) writebuf(p ^ 1, tile + 1);              // write-late into free buffer
    p ^= 1;
  }
}

// ---------------- split-wave flash edge kernel, 2-deep gather pipeline ----------------
// 4 instrs (2 trans), no IEEE div:  tanh(x) = 1 - 2*rcp(exp2(2x*log2e)+1)
__device__ __forceinline__ float fast_tanh(float x) {
  float e = __builtin_amdgcn_exp2f(x * 2.8853900817779268f);  // e^{2x}
  float t = __builtin_amdgcn_rcpf(e + 1.f);
  return __builtin_fmaf(-2.f, t, 1.f);
}

__global__ __launch_bounds__(256) void edge_flash_kernel(
    const ushort* __restrict__ news_projbf, const ushort* __restrict__ company_projbf,
    const float* __restrict__ v, const int* __restrict__ offsets,
    const int* __restrict__ srcs, const ushort* __restrict__ news_xbf,
    float* __restrict__ out) {
  const int c = blockIdx.x;
  const int tid = threadIdx.x;
  const int sl = tid & 31;   // sub-lane within half-wave (owns dims sl*8..sl*8+7)
  const int hw = tid >> 5;   // half-wave id 0..7 (owns edges beg+hw, +8, +16, ...)
  __shared__ float cp[H];
  __shared__ float mW[8], lW[8];
  __shared__ float OW[8][H];  // 8 KB
  cp[tid] = bf2f(company_projbf[(size_t)c * H + tid]);
  __syncthreads();
  const float4 va = *(const float4*)(v + sl * 8);
  const float4 vb = *(const float4*)(v + sl * 8 + 4);
  const float4 ca = *(const float4*)&cp[sl * 8];
  const float4 cb = *(const float4*)&cp[sl * 8 + 4];
  const float vv[8] = {va.x, va.y, va.z, va.w, vb.x, vb.y, vb.z, vb.w};
  const float cq[8] = {ca.x, ca.y, ca.z, ca.w, cb.x, cb.y, cb.z, cb.w};
  const int beg = offsets[c], end = offsets[c + 1];

  float m = -INFINITY, l = 0.f;
  float O[8] = {0.f, 0.f, 0.f, 0.f, 0.f, 0.f, 0.f, 0.f};

  int i = beg + hw;
  if (i < end) {
    bfrag pr0, xr0, pr1 = (bfrag)(short)0, xr1 = (bfrag)(short)0;
    {
      const int s = srcs[i];
      pr0 = *(const bfrag*)(news_projbf + (size_t)s * H + sl * 8);
      xr0 = *(const bfrag*)(news_xbf + (size_t)s * H + sl * 8);
    }
    bool has1 = (i + 8 < end);
    if (has1) {
      const int s = srcs[i + 8];
      pr1 = *(const bfrag*)(news_projbf + (size_t)s * H + sl * 8);
      xr1 = *(const bfrag*)(news_xbf + (size_t)s * H + sl * 8);
    }
    for (;;) {
      const int i2 = i + 16;
      const bool has2 = (i2 < end);                 // half-wave uniform
      bfrag pr2 = (bfrag)(short)0, xr2 = (bfrag)(short)0;
      if (has2) {                                   // 2-deep: 6 loads in flight
        const int s = srcs[i2];
        pr2 = *(const bfrag*)(news_projbf + (size_t)s * H + sl * 8);
        xr2 = *(const bfrag*)(news_xbf + (size_t)s * H + sl * 8);
      }
      float r = 0.f;
#pragma unroll
      for (int j = 0; j < 8; ++j)
        r += fast_tanh(bf2f((ushort)pr0[j]) + cq[j]) * vv[j];
#pragma unroll
      for (int off = 16; off > 0; off >>= 1) r += __shfl_xor(r, off);
      const float mnew = fmaxf(m, r);
      const float alpha = __expf(m - mnew);         // first iter: exp(-inf)=0
      const float pa = __expf(r - mnew);
      l = l * alpha + pa;
#pragma unroll
      for (int j = 0; j < 8; ++j)
        O[j] = O[j] * alpha + pa * bf2f((ushort)xr0[j]);
      m = mnew;
      if (!has1) break;
      pr0 = pr1; xr0 = xr1;                         // shift pipeline
      pr1 = pr2; xr1 = xr2;                         // garbage iff !has2 (unused)
      i += 8;
      has1 = has2;
    }
  }

  // ---- merge 8 half-waves ----
  if (sl == 0) { mW[hw] = m; lW[hw] = l; }
  *(float4*)&OW[hw][sl * 8]     = make_float4(O[0], O[1], O[2], O[3]);
  *(float4*)&OW[hw][sl * 8 + 4] = make_float4(O[4], O[5], O[6], O[7]);
  __syncthreads();
  float mstar = -INFINITY;
#pragma unroll
  for (int w = 0; w < 8; ++w) mstar = fmaxf(mstar, mW[w]);
  float denom = 0.f, val = 0.f;
#pragma unroll
  for (int w = 0; w < 8; ++w) {
    const float sc = (lW[w] > 0.f) ? __expf(mW[w] - mstar) : 0.f;
    denom += lW[w] * sc;
    val += OW[w][tid] * sc;
  }
  out[(size_t)c * H + tid] = val / fmaxf(denom, 1e-9f);
}

// ---------------- launch ----------------
extern "C" void kernel_launch(void* const* d_in, const int* in_sizes, int n_in,
                              void* d_out, int out_size, void* d_ws, size_t ws_size,
                              hipStream_t stream) {
  const float* news_x    = (const float*)d_in[0];
  const float* company_x = (const float*)d_in[1];
  const float* W_news    = (const float*)d_in[2];
  const float* W_company = (const float*)d_in[3];
  const float* v         = (const float*)d_in[4];
  const int*   src       = (const int*)d_in[5];
  const int*   dst       = (const int*)d_in[6];
  const int N = in_sizes[0] / H;
  const int C = in_sizes[1] / H;
  const int E = in_sizes[5];
  float* out = (float*)d_out;

  char* p = (char*)d_ws;
  ushort* news_projbf    = (ushort*)p; p += (size_t)N * H * sizeof(ushort);
  ushort* news_xbf       = (ushort*)p; p += (size_t)N * H * sizeof(ushort);
  ushort* company_projbf = (ushort*)p; p += (size_t)C * H * sizeof(ushort);
  int*    srcs_sorted    = (int*)p;    p += (size_t)E * sizeof(int);
  ushort* Wn_hi          = (ushort*)p; p += (size_t)H * H * sizeof(ushort);
  ushort* Wn_lo          = (ushort*)p; p += (size_t)H * H * sizeof(ushort);
  ushort* Wc_hi          = (ushort*)p; p += (size_t)H * H * sizeof(ushort);
  ushort* Wc_lo          = (ushort*)p; p += (size_t)H * H * sizeof(ushort);
  int*    counts         = (int*)p;    p += (size_t)C * sizeof(int);
  int*    offsets        = (int*)p;    p += (size_t)(C + 1) * sizeof(int);
  int*    cursor         = (int*)p;    p += (size_t)C * sizeof(int);

  hipMemsetAsync(counts, 0, (size_t)C * sizeof(int), stream);
  prep_kernel<<<512 + (E + 255) / 256, 256, 0, stream>>>(
      W_news, W_company, Wn_hi, Wn_lo, Wc_hi, Wc_lo, dst, counts, E);
  scan_kernel<<<1, 1024, 0, stream>>>(counts, offsets, cursor, C);
  fill_kernel<<<(E + 255) / 256, 256, 0, stream>>>(src, dst, cursor, srcs_sorted, E);

  // 512 blocks x 1024 thr. company 157/24=6.5, news 3125/488=6.4 tiles/block.
  const int GC = 24, GN = 488;
  gemm_persist<<<GC + GN, 1024, 0, stream>>>(
      company_x, Wc_hi, Wc_lo, company_projbf, C, GC,
      news_x, Wn_hi, Wn_lo, news_projbf, news_xbf, N);

  edge_flash_kernel<<<C, 256, 0, stream>>>(news_projbf, company_projbf, v, offsets,
                                           srcs_sorted, news_xbf, out);
}